// Round 3
// 810.041 us; speedup vs baseline: 1.1488x; 1.1488x over previous
//
#include <hip/hip_runtime.h>
#include <hip/hip_fp16.h>
#include <stdint.h>

// sLSTM cell, T=512, B=16, H=4 heads, D=256, G=4 gates. fp32 in/out.
//
// R4b = R4 resubmit (round-2 bench died in infra before producing a verdict)
// with fail-fast hardening: spin cap 32768 -> 8192 so a broken protocol
// yields a fast wrong-answer run instead of a container timeout.
// Full dataflow re-derivation done this round: repack blob / register index /
// LDS pair-word layout / quad butterfly / slot+tag protocol all verified
// consistent; protocol is race-free (publisher reaches step t+1 only after
// ALL 16 waves of the chain finished step t) and cannot deadlock.
//
// R4 fixes over R3 (kept):
//  F1: poll via __hip_atomic_load AGENT relaxed (R2-proven coherence bits);
//      R3's raw `sc0` dwordx4 poll was not agent-coherent across XCDs ->
//      stale reads -> spin timeout -> garbage (absmax 0.10).
//  F2: publish tag = t+1 (1..512): zero/stale words never false-validate.
//  F3: weight words laundered through asm("":"+v") after load: compiler
//      cannot rematerialize the loads inside the t-loop, forcing the
//      128-u32 weight slice truly register-resident (R2 showed
//      VGPR_Count=104 -> weights were re-streamed from L2 every step:
//      ~17 GB ~ 500 us of pure L2 traffic).
//
// Structure (R3, wave-autonomous, zero barriers):
//  - 64 chains (b,head), 256 blocks (1/CU), 4 waves each -> 16 waves/chain.
//  - Wave ww in [0,16) owns dout = ww*16 + jl. Lane = jl*4 + kq computes
//    ALL 4 gates of its j over k-quarter kq (128 fdot2, 128 weight regs),
//    then a 2-round DPP quad butterfly gives full-k gate pre-acts in every
//    lane. No __syncthreads anywhere.
//  - x+bias injected pre-butterfly (lane kq==g contributes gate g once).
//  - Every wave runs gate math and publishes its 16 h's immediately.
//  - Exchange: self-validating u32 (hi16=f16(h), lo16=tag), 2-slot
//    ping-pong, relaxed agent scope.
//  - LDS: per-wave 144-u32 padded h-pack row, wave-synchronous only.

#define NTS 512
#define OUTS_ELEMS (NTS * 16 * 1024)   // 8388608 floats of `outs`
#define SPIN_CAP 8192

typedef _Float16 half2v __attribute__((ext_vector_type(2)));

__device__ __forceinline__ float fdot2f(uint32_t a, uint32_t b, float c) {
#if __has_builtin(__builtin_amdgcn_fdot2)
  union U { uint32_t u; half2v h; };
  U ua, ub; ua.u = a; ub.u = b;
  return __builtin_amdgcn_fdot2(ua.h, ub.h, c, false);
#else
  __half2 ha, hb;
  *(uint32_t*)&ha = a; *(uint32_t*)&hb = b;
  float2 fa = __half22float2(ha), fb = __half22float2(hb);
  return fmaf(fa.y, fb.y, fmaf(fa.x, fb.x, c));
#endif
}

// quad_perm DPP cross-lane swaps within each lane-quad:
//   xor1 = [1,0,3,2] -> ctrl 0xB1 ; xor2 = [2,3,0,1] -> ctrl 0x4E
__device__ __forceinline__ float qxor1(float v) {
  return __int_as_float(__builtin_amdgcn_update_dpp(
      0, __float_as_int(v), 0xB1, 0xF, 0xF, true));
}
__device__ __forceinline__ float qxor2(float v) {
  return __int_as_float(__builtin_amdgcn_update_dpp(
      0, __float_as_int(v), 0x4E, 0xF, 0xF, true));
}

// Packed blob (u32 index): ((W*32 + mm)*64 + lane)*4 + dd
//   W = head*16 + ww (wave-in-chain), lane = jl*4 + kq, n = mm*4 + dd:
//   g = n>>5, p = n&31. dout = ww*16 + jl, din = kq*64 + 2p + e.
//   Weff[h,g,dout,din] = rk[h, (din%64)*4+g, dout>>6, (dout&63)*4 + din>>6]
__global__ void repack_weights(const float* __restrict__ rk,
                               uint32_t* __restrict__ wp) {
  int tid = blockIdx.x * 256 + threadIdx.x;   // [0, 524288)
  int dd   = tid & 3;
  int lane = (tid >> 2) & 63;
  int mm   = (tid >> 8) & 31;
  int W    = tid >> 13;                        // head*16 + ww
  int head = W >> 4, ww = W & 15;
  int jl = lane >> 2, kq = lane & 3;
  int n = mm * 4 + dd;
  int g = n >> 5, p = n & 31;
  int dout = ww * 16 + jl;
  uint32_t word = 0;
  #pragma unroll
  for (int e = 0; e < 2; ++e) {
    int klo = 2 * p + e;                       // din % 64
    float v = rk[head * 262144 + (klo * 4 + g) * 1024 +
                 (dout >> 6) * 256 + (dout & 63) * 4 + kq];
    word |= (uint32_t)__half_as_ushort(__float2half(v)) << (16 * e);
  }
  wp[tid] = word;
}

__global__ __launch_bounds__(256, 1) void slstm_main(
    const float* __restrict__ x, const float* __restrict__ bias,
    const uint32_t* __restrict__ wp, uint32_t* hex,
    float* __restrict__ out) {
  // Per-wave padded h-pack row: 4 quarters x (32 words + 4 pad) = 144 u32.
  // Wave-synchronous only (write own 2 pair-words, read own quarter).
  __shared__ __align__(16) uint32_t lhp[4][144];

  // XCD swizzle (perf only; correctness never depends on placement).
  const int bid = blockIdx.x;
  const int xcd = bid & 7, yy = bid >> 3;
  const int q4 = yy & 3, ii = yy >> 2;
  const int cc = xcd * 8 + ii;                 // chain [0,64)
  const int b = cc >> 2, head = cc & 3;
  const int lane = threadIdx.x & 63, w = threadIdx.x >> 6;
  const int ww = q4 * 4 + w;                   // wave-in-chain [0,16)
  const int jl = lane >> 2, kq = lane & 3;
  const int dout = ww * 16 + jl;               // this lane's output dim

  // ---- register-resident weights: 128 u32 = 256 f16 ----
  uint32_t wr_[128];
  {
    const uint4* wp4 = (const uint4*)wp;
    int base = (head * 16 + ww) * 2048 + lane;
    #pragma unroll
    for (int mm = 0; mm < 32; ++mm) {
      uint4 v = wp4[base + mm * 64];
      wr_[mm * 4 + 0] = v.x; wr_[mm * 4 + 1] = v.y;
      wr_[mm * 4 + 2] = v.z; wr_[mm * 4 + 3] = v.w;
    }
  }
  // F3: launder values so the compiler cannot remat the loads inside the
  // t-loop -> weights stay in VGPRs (512 available at 1 wave/SIMD).
  #pragma unroll
  for (int i = 0; i < 128; ++i) asm volatile("" : "+v"(wr_[i]));

  // bias layout quirk (proven in R2): bflat index = g*1024 + head*256 + j
  const float bg = bias[kq * 1024 + head * 256 + dout];
  const int xoff0 = b * 4096 + kq * 1024 + head * 256 + dout;
  float xv = x[xoff0];                         // x_t for t = 0

  const int rd_base = cc * 256 + lane * 4;     // 4 words this lane polls
  const int wr_idx  = cc * 256 + dout;         // word kq==0 lanes publish
  const int out_off = b * 1024 + head * 256 + dout;
  const bool pub = (kq == 0);

  uint32_t* lrow = &lhp[w][0];
  const int widx = (lane >> 4) * 36 + ((2 * lane) & 31);  // write slot (u32)

  float hs = 0.f, cs = 0.f, nns = 0.f, ms = 0.f;

  #pragma unroll 1
  for (int t = 0; t < NTS; ++t) {
    // x+bias injected pre-butterfly: lane kq contributes gate kq exactly once
    float xb = xv + bg;
    float A0 = (kq == 0) ? xb : 0.f;
    float A1 = (kq == 1) ? xb : 0.f;
    float A2 = (kq == 2) ? xb : 0.f;
    float A3 = (kq == 3) ? xb : 0.f;
    float xn = 0.f;
    if (t > 0) {
      // --- acquire h_{t-1}: 4 agent-scope word polls, self-validating ---
      // tag of step s is s+1, so tg = (t-1)+1 = t; stale words never match.
      const uint32_t tg = (uint32_t)t;
      const uint32_t* sp = hex + ((t - 1) & 1) * 16384 + rd_base;
      uint32_t v0, v1, v2, v3; int spins = 0;
      for (;;) {
        v0 = __hip_atomic_load(sp + 0, __ATOMIC_RELAXED, __HIP_MEMORY_SCOPE_AGENT);
        v1 = __hip_atomic_load(sp + 1, __ATOMIC_RELAXED, __HIP_MEMORY_SCOPE_AGENT);
        v2 = __hip_atomic_load(sp + 2, __ATOMIC_RELAXED, __HIP_MEMORY_SCOPE_AGENT);
        v3 = __hip_atomic_load(sp + 3, __ATOMIC_RELAXED, __HIP_MEMORY_SCOPE_AGENT);
        int ok = ((v0 & 0xffffu) == tg) & ((v1 & 0xffffu) == tg) &
                 ((v2 & 0xffffu) == tg) & ((v3 & 0xffffu) == tg);
        if (__all(ok)) break;
        if (++spins > SPIN_CAP) break;         // fail-fast, never hang
      }
      // prefetch next step's x now; drains during dots
      if (t < NTS - 1) xn = x[xoff0 + (t + 1) * 65536];
      // pack h[4L..4L+3] into 2 pair-words, write to own wave's LDS row
      uint32_t p0 = (v0 >> 16) | (v1 & 0xffff0000u);
      uint32_t p1 = (v2 >> 16) | (v3 & 0xffff0000u);
      *(uint64_t*)&lrow[widx] = ((uint64_t)p1 << 32) | (uint64_t)p0;
      // read own k-quarter: 8x ds_read_b128, quad-broadcast addresses
      const uint4* rp = (const uint4*)&lrow[kq * 36];
      #pragma unroll
      for (int c = 0; c < 8; ++c) {
        uint4 hw = rp[c];
        A0 = fdot2f(wr_[c * 4 + 0], hw.x, A0);
        A0 = fdot2f(wr_[c * 4 + 1], hw.y, A0);
        A0 = fdot2f(wr_[c * 4 + 2], hw.z, A0);
        A0 = fdot2f(wr_[c * 4 + 3], hw.w, A0);
        A1 = fdot2f(wr_[32 + c * 4 + 0], hw.x, A1);
        A1 = fdot2f(wr_[32 + c * 4 + 1], hw.y, A1);
        A1 = fdot2f(wr_[32 + c * 4 + 2], hw.z, A1);
        A1 = fdot2f(wr_[32 + c * 4 + 3], hw.w, A1);
        A2 = fdot2f(wr_[64 + c * 4 + 0], hw.x, A2);
        A2 = fdot2f(wr_[64 + c * 4 + 1], hw.y, A2);
        A2 = fdot2f(wr_[64 + c * 4 + 2], hw.z, A2);
        A2 = fdot2f(wr_[64 + c * 4 + 3], hw.w, A2);
        A3 = fdot2f(wr_[96 + c * 4 + 0], hw.x, A3);
        A3 = fdot2f(wr_[96 + c * 4 + 1], hw.y, A3);
        A3 = fdot2f(wr_[96 + c * 4 + 2], hw.z, A3);
        A3 = fdot2f(wr_[96 + c * 4 + 3], hw.w, A3);
      }
    } else {
      xn = x[xoff0 + 65536];
    }

    // quad butterfly (pure VALU): every lane gets full-k gate pre-acts
    A0 += qxor1(A0); A0 += qxor2(A0);
    A1 += qxor1(A1); A1 += qxor2(A1);
    A2 += qxor1(A2); A2 += qxor2(A2);
    A3 += qxor1(A3); A3 += qxor2(A3);

    // state update (matches reference; all(n==0) <=> t==0).
    // Fast forms: err ~1e-7 << f16-exchange noise (~1e-3).
    float ri = A0, rf = A1, rz = A2, ro = A3;
    float lsf = fminf(rf, 0.f) - __logf(1.f + __expf(-fabsf(rf)));
    float lf = ms + lsf;
    float mnew = (t == 0) ? ri : fmaxf(ri, lf);
    float ig = __expf(ri - mnew);
    float fg = __expf(lf - mnew);
    float e2z = __expf(2.f * rz);
    float tz = 1.f - 2.f / (e2z + 1.f);          // tanh(rz)
    float cnew = fg * cs + ig * tz;
    float nnew = fg * hs + ig;                   // reference uses h here
    float hnew = cnew / ((1.f + __expf(-ro)) * nnew);  // og*cnew/nnew fused
    hs = hnew; cs = cnew; nns = nnew; ms = mnew;

    unsigned short hf = __half_as_ushort(__float2half(hnew));
    if (pub) {
      // publish FIRST (critical path), then the out store
      uint32_t wword = ((uint32_t)hf << 16) | (uint32_t)(t + 1);
      __hip_atomic_store(hex + (t & 1) * 16384 + wr_idx, wword,
                         __ATOMIC_RELAXED, __HIP_MEMORY_SCOPE_AGENT);
      out[t * 16384 + out_off] = hnew;
    }
    xv = xn;
  }

  // final_state: stack (h, c, n, m)
  if (pub) {
    float* fs = out + OUTS_ELEMS;
    fs[out_off] = hs;
    fs[16384 + out_off] = cs;
    fs[32768 + out_off] = nns;
    fs[49152 + out_off] = ms;
  }
}

extern "C" void kernel_launch(void* const* d_in, const int* in_sizes, int n_in,
                              void* d_out, int out_size, void* d_ws,
                              size_t ws_size, hipStream_t stream) {
  const float* x    = (const float*)d_in[0];  // (512,16,4096)
  const float* rk   = (const float*)d_in[1];  // (4,256,4,256)
  const float* bias = (const float*)d_in[2];  // (4,4,256)
  uint32_t* wp  = (uint32_t*)d_ws;                         // 2 MB packed f16
  uint32_t* hex = (uint32_t*)((char*)d_ws + (1u << 21));   // 128 KB exchange
  float* out = (float*)d_out;

  repack_weights<<<2048, 256, 0, stream>>>(rk, wp);
  slstm_main<<<256, 256, 0, stream>>>(x, bias, wp, hex, out);
}